// Round 1
// baseline (213.047 us; speedup 1.0000x reference)
//
#include <hip/hip_runtime.h>

#define B_   8
#define C_   64
#define H_   128
#define W_   128
#define HW   16384
#define CHW  (C_*HW)
#define NPIX (B_*HW)
#define CR   32
#define KK   9
#define EPS_ 1e-5f

__device__ __forceinline__ float sgnf(float v){
    return (float)((v > 0.f) - (v < 0.f));
}

// ---------------------------------------------------------------- prep ----
// Binarize weights. Wp[o*64+i] (pre), WrT[i*32+r] (reduce, TRANSPOSED),
// Ws[j*32+r] (span), Wq[o*64+i] (post).
__global__ void prep(const float* __restrict__ pre_w, const float* __restrict__ red_w,
                     const float* __restrict__ span_w, const float* __restrict__ post_w,
                     float* __restrict__ Wp, float* __restrict__ WrT,
                     float* __restrict__ Ws, float* __restrict__ Wq){
    int t = threadIdx.x;
    if (t < 64){
        float s = 0.f;
        for (int i = 0; i < 64; i++) s += fabsf(pre_w[t*64+i]);
        s *= (1.f/64.f);
        for (int i = 0; i < 64; i++) Wp[t*64+i] = s * sgnf(pre_w[t*64+i]);
        float s2 = 0.f;
        for (int i = 0; i < 64; i++) s2 += fabsf(post_w[t*64+i]);
        s2 *= (1.f/64.f);
        for (int i = 0; i < 64; i++) Wq[t*64+i] = s2 * sgnf(post_w[t*64+i]);
    }
    if (t < 32){
        float s = 0.f;
        for (int i = 0; i < 64; i++) s += fabsf(red_w[t*64+i]);
        s *= (1.f/64.f);
        for (int i = 0; i < 64; i++) WrT[i*32+t] = s * sgnf(red_w[t*64+i]);
    }
    if (t < 9){
        float s = 0.f;
        for (int r = 0; r < 32; r++) s += fabsf(span_w[t*32+r]);
        s *= (1.f/32.f);
        for (int r = 0; r < 32; r++) Ws[t*32+r] = s * sgnf(span_w[t*32+r]);
    }
}

// ------------------------------------------------------------ conv_pre ----
// y1[b,o,p] = sum_i Wp[o,i] * (sign(x[b,i,p]) + bias[i])
__global__ __launch_bounds__(256) void conv_pre(const float* __restrict__ x,
                                                const float* __restrict__ bias,
                                                const float* __restrict__ Wp,
                                                float* __restrict__ y1){
    __shared__ __align__(16) float Wl[64*64];
    __shared__ float bl[64];
    for (int i = threadIdx.x; i < 64*64; i += 256) Wl[i] = Wp[i];
    if (threadIdx.x < 64) bl[threadIdx.x] = bias[threadIdx.x];
    __syncthreads();

    int p   = blockIdx.x*256 + threadIdx.x;   // 0..NPIX-1
    int b   = p >> 14;
    int pix = p & (HW-1);
    const float* xb = x + (size_t)b*CHW + pix;

    float s[64];
#pragma unroll
    for (int i = 0; i < 64; i++){
        float v = xb[(size_t)i*HW];
        s[i] = sgnf(v) + bl[i];
    }

    float* yb = y1 + (size_t)b*CHW + pix;
#pragma unroll 2
    for (int o = 0; o < 64; o++){
        const float4* w4 = reinterpret_cast<const float4*>(&Wl[o*64]);
        float a0=0.f, a1=0.f, a2=0.f, a3=0.f;
#pragma unroll
        for (int q = 0; q < 16; q++){
            float4 w = w4[q];
            a0 = fmaf(w.x, s[4*q+0], a0);
            a1 = fmaf(w.y, s[4*q+1], a1);
            a2 = fmaf(w.z, s[4*q+2], a2);
            a3 = fmaf(w.w, s[4*q+3], a3);
        }
        yb[(size_t)o*HW] = (a0+a1) + (a2+a3);
    }
}

// ------------------------------------------------------------ bn_stats ----
// One block per channel. scale/shift so that BN(x) = scale*x + shift.
__global__ __launch_bounds__(1024) void bn_stats(const float* __restrict__ X,
                                                 const float* __restrict__ gamma,
                                                 const float* __restrict__ beta,
                                                 float* __restrict__ scale,
                                                 float* __restrict__ shift){
    int c   = blockIdx.x;
    int tid = threadIdx.x;
    float s = 0.f, q = 0.f;
    const float* base = X + (size_t)c*HW;
    for (int b = 0; b < B_; b++){
        const float* p = base + (size_t)b*CHW;
#pragma unroll
        for (int k = 0; k < HW/1024; k++){
            float v = p[tid + k*1024];
            s += v; q += v*v;
        }
    }
    for (int off = 32; off > 0; off >>= 1){
        s += __shfl_down(s, off);
        q += __shfl_down(q, off);
    }
    __shared__ float ls[16], lq[16];
    int w = tid >> 6, lane = tid & 63;
    if (lane == 0){ ls[w] = s; lq[w] = q; }
    __syncthreads();
    if (tid == 0){
        float S = 0.f, Q = 0.f;
        for (int i = 0; i < 16; i++){ S += ls[i]; Q += lq[i]; }
        float mean = S * (1.f/(float)NPIX);
        float var  = Q * (1.f/(float)NPIX) - mean*mean;
        var = fmaxf(var, 0.f);
        float sc = gamma[c] * rsqrtf(var + EPS_);
        scale[c] = sc;
        shift[c] = beta[c] - mean*sc;
    }
}

// --------------------------------------------------------------- invol ----
// Fused: z2 = prelu(BN1(y1)) + mid_bias (tile+halo in LDS), ker = span(reduce(z2)),
// y2 = 3x3 involution. Tile 16x8 per block, 256 threads, 1024 blocks.
__global__ __launch_bounds__(256) void invol(const float* __restrict__ y1,
                                             const float* __restrict__ sc1,
                                             const float* __restrict__ sh1,
                                             const float* __restrict__ pa,
                                             const float* __restrict__ mb,
                                             const float* __restrict__ WrT,
                                             const float* __restrict__ Ws,
                                             float* __restrict__ y2){
    __shared__ float zt[64*10*18];   // [i][y][x]  46080 B
    __shared__ float tb[128*32];     // t per (pix,r); reused for ker  16384 B
    __shared__ float sc1l[64], sh1l[64], al[64], mbl[64];

    int tid = threadIdx.x;
    int bb  = blockIdx.x;
    int b   = bb >> 7;
    int rem = bb & 127;
    int y0  = (rem >> 3) * 8;
    int x0  = (rem & 7) * 16;

    if (tid < 64){
        sc1l[tid] = sc1[tid]; sh1l[tid] = sh1[tid];
        al[tid]   = pa[tid];  mbl[tid]  = mb[tid];
    }
    __syncthreads();

    // load tile + halo, apply BN1 + prelu + mid_bias; zero outside image
    for (int e = tid; e < 64*10*18; e += 256){
        int i   = e / 180;
        int r   = e - i*180;
        int yy  = r / 18;
        int xx  = r - yy*18;
        int gy  = y0 + yy - 1;
        int gx  = x0 + xx - 1;
        float v = 0.f;
        if ((unsigned)gy < 128u && (unsigned)gx < 128u){
            float u = y1[((size_t)(b*64+i))*HW + (size_t)gy*128 + gx];
            float w = fmaf(sc1l[i], u, sh1l[i]);
            v = fmaxf(w, 0.f) + al[i]*fminf(w, 0.f) + mbl[i];
        }
        zt[e] = v;
    }
    __syncthreads();

    // Phase A: t[pix][r] = sum_i WrT[i][r] * z2_center[i]; r split across wave halves
    {
        int half = __builtin_amdgcn_readfirstlane(tid >> 7);  // wave-uniform
        int r0   = half * 16;
        int pix  = tid & 127;
        int ly   = pix >> 4, lx = pix & 15;
        float acc[16];
#pragma unroll
        for (int r = 0; r < 16; r++) acc[r] = 0.f;
        for (int i = 0; i < 64; i++){
            float zv = zt[(i*10 + ly + 1)*18 + lx + 1];
#pragma unroll
            for (int r = 0; r < 16; r++)
                acc[r] = fmaf(WrT[i*32 + r0 + r], zv, acc[r]);
        }
#pragma unroll
        for (int r = 0; r < 16; r++) tb[pix*32 + r0 + r] = acc[r];
    }
    __syncthreads();

    // Phase B: ker[pix][j] = sum_r Ws[j][r] * t[pix][r]  (into regs, then reuse tb)
    float kreg[5];
    {
        int n = 0;
        for (int task = tid; task < 128*9; task += 256){
            int pix = task / 9;
            int j   = task - pix*9;
            float a = 0.f;
#pragma unroll
            for (int r = 0; r < 32; r++)
                a = fmaf(Ws[j*32+r], tb[pix*32+r], a);
            kreg[n++] = a;
        }
    }
    __syncthreads();
    {
        int n = 0;
        for (int task = tid; task < 128*9; task += 256) tb[task] = kreg[n++];
    }
    __syncthreads();

    // Phase C: y2[b,c,pix] = sum_{dy,dx} z2[c, nbr] * ker[pix, dy*3+dx]
    {
        int pix = tid & 127;
        int c0  = tid >> 7;             // 0 or 1 (wave-uniform)
        int ly  = pix >> 4, lx = pix & 15;
        float kb[9];
#pragma unroll
        for (int j = 0; j < 9; j++) kb[j] = tb[pix*9 + j];
        size_t obase = (size_t)(b*64)*HW + (size_t)(y0+ly)*128 + (x0+lx);
        for (int cc = 0; cc < 32; cc++){
            int c = c0 + cc*2;
            float a = 0.f;
#pragma unroll
            for (int dy = 0; dy < 3; dy++)
#pragma unroll
                for (int dx = 0; dx < 3; dx++)
                    a = fmaf(zt[(c*10 + ly + dy)*18 + lx + dx], kb[dy*3+dx], a);
            y2[obase + (size_t)c*HW] = a;
        }
    }
}

// ----------------------------------------------------------- conv_post ----
// y3[b,o,p] = sum_i Wq[o,i] * (relu(BN2(y2[b,i,p])) + post_bias[i])
__global__ __launch_bounds__(256) void conv_post(const float* __restrict__ y2,
                                                 const float* __restrict__ sc2,
                                                 const float* __restrict__ sh2,
                                                 const float* __restrict__ pbias,
                                                 const float* __restrict__ Wq,
                                                 float* __restrict__ y3){
    __shared__ __align__(16) float Wl[64*64];
    __shared__ float scl[64], shl[64], pbl[64];
    for (int i = threadIdx.x; i < 64*64; i += 256) Wl[i] = Wq[i];
    if (threadIdx.x < 64){
        scl[threadIdx.x] = sc2[threadIdx.x];
        shl[threadIdx.x] = sh2[threadIdx.x];
        pbl[threadIdx.x] = pbias[threadIdx.x];
    }
    __syncthreads();

    int p   = blockIdx.x*256 + threadIdx.x;
    int b   = p >> 14;
    int pix = p & (HW-1);
    const float* yb = y2 + (size_t)b*CHW + pix;

    float s[64];
#pragma unroll
    for (int i = 0; i < 64; i++){
        float v = yb[(size_t)i*HW];
        float u = fmaf(scl[i], v, shl[i]);
        s[i] = fmaxf(u, 0.f) + pbl[i];   // relu; prelu(x>=0)=x
    }

    float* ob = y3 + (size_t)b*CHW + pix;
#pragma unroll 2
    for (int o = 0; o < 64; o++){
        const float4* w4 = reinterpret_cast<const float4*>(&Wl[o*64]);
        float a0=0.f, a1=0.f, a2=0.f, a3=0.f;
#pragma unroll
        for (int q = 0; q < 16; q++){
            float4 w = w4[q];
            a0 = fmaf(w.x, s[4*q+0], a0);
            a1 = fmaf(w.y, s[4*q+1], a1);
            a2 = fmaf(w.z, s[4*q+2], a2);
            a3 = fmaf(w.w, s[4*q+3], a3);
        }
        ob[(size_t)o*HW] = (a0+a1) + (a2+a3);
    }
}

// --------------------------------------------------------------- final ----
// out = BN3(y3) + x
__global__ __launch_bounds__(256) void finalk(const float* __restrict__ y3,
                                              const float* __restrict__ x,
                                              const float* __restrict__ sc,
                                              const float* __restrict__ sh,
                                              float* __restrict__ out){
    int i4 = blockIdx.x*256 + threadIdx.x;      // float4 index, 0..2097151
    int c  = (i4 >> 12) & 63;
    float4 a = reinterpret_cast<const float4*>(y3)[i4];
    float4 b = reinterpret_cast<const float4*>(x)[i4];
    float s = sc[c], t = sh[c];
    float4 r;
    r.x = fmaf(s, a.x, t) + b.x;
    r.y = fmaf(s, a.y, t) + b.y;
    r.z = fmaf(s, a.z, t) + b.z;
    r.w = fmaf(s, a.w, t) + b.w;
    reinterpret_cast<float4*>(out)[i4] = r;
}

// -------------------------------------------------------------- launch ----
extern "C" void kernel_launch(void* const* d_in, const int* in_sizes, int n_in,
                              void* d_out, int out_size, void* d_ws, size_t ws_size,
                              hipStream_t stream){
    const float* x        = (const float*)d_in[0];
    const float* pre_bias = (const float*)d_in[1];
    const float* pre_w    = (const float*)d_in[2];
    const float* pre_g    = (const float*)d_in[3];
    const float* pre_b    = (const float*)d_in[4];
    const float* pre_a    = (const float*)d_in[5];
    const float* mid_bias = (const float*)d_in[6];
    const float* red_w    = (const float*)d_in[7];
    const float* span_w   = (const float*)d_in[8];
    const float* mid_g    = (const float*)d_in[9];
    const float* mid_b    = (const float*)d_in[10];
    const float* post_bias= (const float*)d_in[12];
    const float* post_w   = (const float*)d_in[13];
    const float* post_g   = (const float*)d_in[14];
    const float* post_b   = (const float*)d_in[15];

    float* ws  = (float*)d_ws;
    float* buf = ws;                       // y1, later y3 (8388608 floats)
    float* Wp  = ws + 8388608;
    float* WrT = Wp + 4096;
    float* Wsp = WrT + 2048;
    float* Wq  = Wsp + 288;
    float* sc1 = Wq + 4096;  float* sh1 = sc1 + 64;
    float* sc2 = sh1 + 64;   float* sh2 = sc2 + 64;
    float* sc3 = sh2 + 64;   float* sh3 = sc3 + 64;

    float* y2  = (float*)d_out;            // scratch until finalk overwrites
    float* out = (float*)d_out;

    hipLaunchKernelGGL(prep, dim3(1), dim3(64), 0, stream,
                       pre_w, red_w, span_w, post_w, Wp, WrT, Wsp, Wq);
    hipLaunchKernelGGL(conv_pre, dim3(NPIX/256), dim3(256), 0, stream,
                       x, pre_bias, Wp, buf);
    hipLaunchKernelGGL(bn_stats, dim3(64), dim3(1024), 0, stream,
                       buf, pre_g, pre_b, sc1, sh1);
    hipLaunchKernelGGL(invol, dim3(1024), dim3(256), 0, stream,
                       buf, sc1, sh1, pre_a, mid_bias, WrT, Wsp, y2);
    hipLaunchKernelGGL(bn_stats, dim3(64), dim3(1024), 0, stream,
                       y2, mid_g, mid_b, sc2, sh2);
    hipLaunchKernelGGL(conv_post, dim3(NPIX/256), dim3(256), 0, stream,
                       y2, sc2, sh2, post_bias, Wq, buf);
    hipLaunchKernelGGL(bn_stats, dim3(64), dim3(1024), 0, stream,
                       buf, post_g, post_b, sc3, sh3);
    hipLaunchKernelGGL(finalk, dim3(NPIX*64/4/256), dim3(256), 0, stream,
                       buf, x, sc3, sh3, out);
}

// Round 2
// 198.907 us; speedup vs baseline: 1.0711x; 1.0711x over previous
//
#include <hip/hip_runtime.h>

#define B_   8
#define C_   64
#define HW   16384
#define CHW  (C_*HW)
#define NPIX (B_*HW)
#define EPS_ 1e-5f

__device__ __forceinline__ float sgnf(float v){
    return (float)((v > 0.f) - (v < 0.f));
}

// ---------------------------------------------------------------- prep ----
// Wp[o*64+i] (pre, binarized), Wq[o*64+i] (post, binarized),
// M[i*9+j] = sum_r bws[j][r]*bwr[r][i]  (collapsed reduce+span weights)
__global__ void prep(const float* __restrict__ pre_w, const float* __restrict__ red_w,
                     const float* __restrict__ span_w, const float* __restrict__ post_w,
                     float* __restrict__ Wp, float* __restrict__ Wq,
                     float* __restrict__ M){
    __shared__ float sr[32], ss[9];
    int t = threadIdx.x;
    if (t < 64){
        float s = 0.f;
        for (int i = 0; i < 64; i++) s += fabsf(pre_w[t*64+i]);
        s *= (1.f/64.f);
        for (int i = 0; i < 64; i++) Wp[t*64+i] = s * sgnf(pre_w[t*64+i]);
        float s2 = 0.f;
        for (int i = 0; i < 64; i++) s2 += fabsf(post_w[t*64+i]);
        s2 *= (1.f/64.f);
        for (int i = 0; i < 64; i++) Wq[t*64+i] = s2 * sgnf(post_w[t*64+i]);
    }
    if (t < 32){
        float s = 0.f;
        for (int i = 0; i < 64; i++) s += fabsf(red_w[t*64+i]);
        sr[t] = s * (1.f/64.f);
    }
    if (t < 9){
        float s = 0.f;
        for (int r = 0; r < 32; r++) s += fabsf(span_w[t*32+r]);
        ss[t] = s * (1.f/32.f);
    }
    __syncthreads();
    if (t < 64){
        for (int j = 0; j < 9; j++){
            float m = 0.f;
            for (int r = 0; r < 32; r++)
                m += sgnf(span_w[j*32+r]) * sr[r] * sgnf(red_w[r*64+t]);
            M[t*9+j] = ss[j] * m;
        }
    }
}

// ------------------------------------------------------------ conv_pre ----
// y1[b,o,p] = sum_i Wp[o,i] * (sign(x[b,i,p]) + bias[i]); weights via s_load
__global__ __launch_bounds__(256) void conv_pre(const float* __restrict__ x,
                                                const float* __restrict__ bias,
                                                const float* __restrict__ Wp,
                                                float* __restrict__ y1){
    int p   = blockIdx.x*256 + threadIdx.x;
    int b   = p >> 14;
    int pix = p & (HW-1);
    const float* xb = x + (size_t)b*CHW + pix;

    float s[64];
#pragma unroll
    for (int i = 0; i < 64; i++)
        s[i] = sgnf(xb[(size_t)i*HW]) + bias[i];

    float* yb = y1 + (size_t)b*CHW + pix;
#pragma unroll 4
    for (int o = 0; o < 64; o++){
        float a0=0.f, a1=0.f, a2=0.f, a3=0.f;
#pragma unroll
        for (int q = 0; q < 16; q++){
            a0 = fmaf(Wp[o*64+4*q+0], s[4*q+0], a0);
            a1 = fmaf(Wp[o*64+4*q+1], s[4*q+1], a1);
            a2 = fmaf(Wp[o*64+4*q+2], s[4*q+2], a2);
            a3 = fmaf(Wp[o*64+4*q+3], s[4*q+3], a3);
        }
        yb[(size_t)o*HW] = (a0+a1) + (a2+a3);
    }
}

// ----------------------------------------------------------------- bnp ----
// Per-(channel, slice) partial sums. grid 512: c = bid&63, slice = bid>>6.
__global__ __launch_bounds__(256) void bnp(const float* __restrict__ X,
                                           float2* __restrict__ part){
    int bid = blockIdx.x;
    int c   = bid & 63, sl = bid >> 6;
    int tid = threadIdx.x;
    const float* base = X + (size_t)c*HW + sl*2048;
    float s = 0.f, q = 0.f;
#pragma unroll
    for (int b = 0; b < 8; b++){
        const float4* p4 = reinterpret_cast<const float4*>(base + (size_t)b*CHW);
        float4 v1 = p4[tid];
        float4 v2 = p4[tid+256];
        s += (v1.x+v1.y) + (v1.z+v1.w) + (v2.x+v2.y) + (v2.z+v2.w);
        q += (v1.x*v1.x+v1.y*v1.y) + (v1.z*v1.z+v1.w*v1.w)
           + (v2.x*v2.x+v2.y*v2.y) + (v2.z*v2.z+v2.w*v2.w);
    }
    for (int off = 32; off > 0; off >>= 1){
        s += __shfl_down(s, off);
        q += __shfl_down(q, off);
    }
    __shared__ float2 wp[4];
    if ((tid & 63) == 0) wp[tid>>6] = make_float2(s, q);
    __syncthreads();
    if (tid == 0){
        float S = 0.f, Q = 0.f;
        for (int w = 0; w < 4; w++){ S += wp[w].x; Q += wp[w].y; }
        part[bid] = make_float2(S, Q);
    }
}

// Combine 8 slice-partials into per-channel scale/shift (threads 0..63).
__device__ __forceinline__ void bn_combine(const float2* __restrict__ part,
                                           const float* __restrict__ gamma,
                                           const float* __restrict__ beta,
                                           float* scl, float* shl, int tid){
    if (tid < 64){
        float S = 0.f, Q = 0.f;
#pragma unroll
        for (int sl = 0; sl < 8; sl++){
            float2 v = part[sl*64 + tid];
            S += v.x; Q += v.y;
        }
        float mean = S * (1.f/(float)NPIX);
        float var  = fmaxf(Q * (1.f/(float)NPIX) - mean*mean, 0.f);
        float sc = gamma[tid] * rsqrtf(var + EPS_);
        scl[tid] = sc;
        shl[tid] = beta[tid] - mean*sc;
    }
}

// --------------------------------------------------------------- invol ----
// z2 = prelu(BN1(y1)) + mid_bias (tile 16x8 + halo in LDS),
// ker[pix][j] = sum_i M[i][j]*z2_center[i], y2 = 3x3 involution.
__global__ __launch_bounds__(256) void invol(const float* __restrict__ y1,
                                             const float2* __restrict__ part1,
                                             const float* __restrict__ gamma,
                                             const float* __restrict__ beta,
                                             const float* __restrict__ pa,
                                             const float* __restrict__ mb,
                                             const float* __restrict__ M,
                                             float* __restrict__ y2){
    __shared__ float zt[64*180];     // [i][y(10)][x(18)]  46080 B
    __shared__ float tb[128*9];      // ker                 4608 B
    __shared__ float scl[64], shl[64], al[64], mbl[64];

    int tid = threadIdx.x;
    bn_combine(part1, gamma, beta, scl, shl, tid);
    if (tid < 64){ al[tid] = pa[tid]; mbl[tid] = mb[tid]; }
    __syncthreads();

    int bb  = blockIdx.x;
    int b   = bb >> 7;
    int rem = bb & 127;
    int y0  = (rem >> 3) * 8;
    int x0  = (rem & 7) * 16;

    for (int e = tid; e < 64*180; e += 256){
        int i  = e / 180;
        int r  = e - i*180;
        int yy = r / 18;
        int xx = r - yy*18;
        int gy = y0 + yy - 1;
        int gx = x0 + xx - 1;
        float v = 0.f;
        if ((unsigned)gy < 128u && (unsigned)gx < 128u){
            float u = y1[((size_t)(b*64+i))*HW + gy*128 + gx];
            float w = fmaf(scl[i], u, shl[i]);
            v = fmaxf(w, 0.f) + al[i]*fminf(w, 0.f) + mbl[i];
        }
        zt[e] = v;
    }
    __syncthreads();

    // ker: 128 threads, one pixel each; M via wave-uniform scalar loads
    if (tid < 128){
        int ly = tid >> 4, lx = tid & 15;
        float acc[9];
#pragma unroll
        for (int j = 0; j < 9; j++) acc[j] = 0.f;
        const float* zc = &zt[(ly+1)*18 + lx + 1];
        for (int i = 0; i < 64; i++){
            float zv = zc[i*180];
#pragma unroll
            for (int j = 0; j < 9; j++)
                acc[j] = fmaf(M[i*9+j], zv, acc[j]);
        }
#pragma unroll
        for (int j = 0; j < 9; j++) tb[tid*9+j] = acc[j];
    }
    __syncthreads();

    // involution gather
    {
        int pix = tid & 127;
        int c0  = tid >> 7;
        int ly  = pix >> 4, lx = pix & 15;
        float kb[9];
#pragma unroll
        for (int j = 0; j < 9; j++) kb[j] = tb[pix*9 + j];
        size_t obase = (size_t)(b*64)*HW + (size_t)(y0+ly)*128 + (x0+lx);
        const float* zb = &zt[ly*18 + lx];
        for (int cc = 0; cc < 32; cc++){
            int c = c0 + cc*2;
            const float* z = zb + c*180;
            float a = 0.f;
#pragma unroll
            for (int dy = 0; dy < 3; dy++)
#pragma unroll
                for (int dx = 0; dx < 3; dx++)
                    a = fmaf(z[dy*18+dx], kb[dy*3+dx], a);
            y2[obase + (size_t)c*HW] = a;
        }
    }
}

// ----------------------------------------------------------- conv_post ----
// y3 = Wq * (relu(BN2(y2)) + post_bias)
__global__ __launch_bounds__(256) void conv_post(const float* __restrict__ y2,
                                                 const float2* __restrict__ part2,
                                                 const float* __restrict__ gamma,
                                                 const float* __restrict__ beta,
                                                 const float* __restrict__ pbias,
                                                 const float* __restrict__ Wq,
                                                 float* __restrict__ y3){
    __shared__ float scl[64], shl[64];
    int tid = threadIdx.x;
    bn_combine(part2, gamma, beta, scl, shl, tid);
    __syncthreads();

    int p   = blockIdx.x*256 + tid;
    int b   = p >> 14;
    int pix = p & (HW-1);
    const float* yb = y2 + (size_t)b*CHW + pix;

    float s[64];
#pragma unroll
    for (int i = 0; i < 64; i++){
        float u = fmaf(scl[i], yb[(size_t)i*HW], shl[i]);
        s[i] = fmaxf(u, 0.f) + pbias[i];
    }

    float* ob = y3 + (size_t)b*CHW + pix;
#pragma unroll 4
    for (int o = 0; o < 64; o++){
        float a0=0.f, a1=0.f, a2=0.f, a3=0.f;
#pragma unroll
        for (int q = 0; q < 16; q++){
            a0 = fmaf(Wq[o*64+4*q+0], s[4*q+0], a0);
            a1 = fmaf(Wq[o*64+4*q+1], s[4*q+1], a1);
            a2 = fmaf(Wq[o*64+4*q+2], s[4*q+2], a2);
            a3 = fmaf(Wq[o*64+4*q+3], s[4*q+3], a3);
        }
        ob[(size_t)o*HW] = (a0+a1) + (a2+a3);
    }
}

// --------------------------------------------------------------- final ----
// out = BN3(y3) + x;  grid-stride, 2048 blocks x 4 float4-iters
__global__ __launch_bounds__(256) void finalk(const float* __restrict__ y3,
                                              const float* __restrict__ x,
                                              const float2* __restrict__ part3,
                                              const float* __restrict__ gamma,
                                              const float* __restrict__ beta,
                                              float* __restrict__ out){
    __shared__ float scl[64], shl[64];
    int tid = threadIdx.x;
    bn_combine(part3, gamma, beta, scl, shl, tid);
    __syncthreads();
#pragma unroll
    for (int it = 0; it < 4; it++){
        int i4 = blockIdx.x*1024 + it*256 + tid;
        int c  = (i4 >> 12) & 63;
        float4 a  = reinterpret_cast<const float4*>(y3)[i4];
        float4 bx = reinterpret_cast<const float4*>(x)[i4];
        float s = scl[c], t = shl[c];
        float4 r;
        r.x = fmaf(s, a.x, t) + bx.x;
        r.y = fmaf(s, a.y, t) + bx.y;
        r.z = fmaf(s, a.z, t) + bx.z;
        r.w = fmaf(s, a.w, t) + bx.w;
        reinterpret_cast<float4*>(out)[i4] = r;
    }
}

// -------------------------------------------------------------- launch ----
extern "C" void kernel_launch(void* const* d_in, const int* in_sizes, int n_in,
                              void* d_out, int out_size, void* d_ws, size_t ws_size,
                              hipStream_t stream){
    const float* x        = (const float*)d_in[0];
    const float* pre_bias = (const float*)d_in[1];
    const float* pre_w    = (const float*)d_in[2];
    const float* pre_g    = (const float*)d_in[3];
    const float* pre_b    = (const float*)d_in[4];
    const float* pre_a    = (const float*)d_in[5];
    const float* mid_bias = (const float*)d_in[6];
    const float* red_w    = (const float*)d_in[7];
    const float* span_w   = (const float*)d_in[8];
    const float* mid_g    = (const float*)d_in[9];
    const float* mid_b    = (const float*)d_in[10];
    const float* post_bias= (const float*)d_in[12];
    const float* post_w   = (const float*)d_in[13];
    const float* post_g   = (const float*)d_in[14];
    const float* post_b   = (const float*)d_in[15];

    float* ws  = (float*)d_ws;
    float* buf = ws;                         // y1, later y3 (8388608 floats)
    float* Wp  = ws + 8388608;               // 4096
    float* Wq  = Wp + 4096;                  // 4096
    float* M   = Wq + 4096;                  // 576 (pad to 640)
    float2* part1 = (float2*)(M + 640);      // 512 float2
    float2* part2 = part1 + 512;
    float2* part3 = part2 + 512;

    float* y2  = (float*)d_out;              // scratch until finalk overwrites
    float* out = (float*)d_out;

    hipLaunchKernelGGL(prep, dim3(1), dim3(64), 0, stream,
                       pre_w, red_w, span_w, post_w, Wp, Wq, M);
    hipLaunchKernelGGL(conv_pre, dim3(NPIX/256), dim3(256), 0, stream,
                       x, pre_bias, Wp, buf);
    hipLaunchKernelGGL(bnp, dim3(512), dim3(256), 0, stream, buf, part1);
    hipLaunchKernelGGL(invol, dim3(1024), dim3(256), 0, stream,
                       buf, part1, pre_g, pre_b, pre_a, mid_bias, M, y2);
    hipLaunchKernelGGL(bnp, dim3(512), dim3(256), 0, stream, y2, part2);
    hipLaunchKernelGGL(conv_post, dim3(NPIX/256), dim3(256), 0, stream,
                       y2, part2, mid_g, mid_b, post_bias, Wq, buf);
    hipLaunchKernelGGL(bnp, dim3(512), dim3(256), 0, stream, buf, part3);
    hipLaunchKernelGGL(finalk, dim3(2048), dim3(256), 0, stream,
                       buf, x, part3, post_g, post_b, out);
}

// Round 3
// 164.478 us; speedup vs baseline: 1.2953x; 1.2093x over previous
//
#include <hip/hip_runtime.h>

#define B_   8
#define C_   64
#define HW   16384
#define CHW  (C_*HW)
#define NPIX (B_*HW)
#define EPS_ 1e-5f

typedef unsigned short u16;
typedef unsigned int   u32;

__device__ __forceinline__ float sgnf(float v){ return (float)((v>0.f)-(v<0.f)); }
__device__ __forceinline__ float bf2f(u16 h){ return __uint_as_float(((u32)h)<<16); }
__device__ __forceinline__ u16 f2bf(float f){
    u32 u = __float_as_uint(f);
    u += 0x7fffu + ((u>>16)&1u);
    return (u16)(u>>16);
}
__device__ __forceinline__ u32 pack2(float a, float b){
    return (u32)f2bf(a) | ((u32)f2bf(b)<<16);
}

// ---------------------------------------------------------------- prep ----
__global__ void prep(const float* __restrict__ pre_w, const float* __restrict__ red_w,
                     const float* __restrict__ span_w, const float* __restrict__ post_w,
                     float* __restrict__ Wp, float* __restrict__ Wq,
                     float* __restrict__ M){
    __shared__ float sr[32], ss[9];
    int t = threadIdx.x;
    if (t < 64){
        float s = 0.f;
        for (int i = 0; i < 64; i++) s += fabsf(pre_w[t*64+i]);
        s *= (1.f/64.f);
        for (int i = 0; i < 64; i++) Wp[t*64+i] = s * sgnf(pre_w[t*64+i]);
        float s2 = 0.f;
        for (int i = 0; i < 64; i++) s2 += fabsf(post_w[t*64+i]);
        s2 *= (1.f/64.f);
        for (int i = 0; i < 64; i++) Wq[t*64+i] = s2 * sgnf(post_w[t*64+i]);
    }
    if (t < 32){
        float s = 0.f;
        for (int i = 0; i < 64; i++) s += fabsf(red_w[t*64+i]);
        sr[t] = s * (1.f/64.f);
    }
    if (t < 9){
        float s = 0.f;
        for (int r = 0; r < 32; r++) s += fabsf(span_w[t*32+r]);
        ss[t] = s * (1.f/32.f);
    }
    __syncthreads();
    if (t < 64){
        for (int j = 0; j < 9; j++){
            float m = 0.f;
            for (int r = 0; r < 32; r++)
                m += sgnf(span_w[j*32+r]) * sr[r] * sgnf(red_w[r*64+t]);
            M[t*9+j] = ss[j] * m;
        }
    }
}

// ------------------------------------------------------------ conv_pre ----
// y1[b,o,p] = f2bf( sum_i Wp[o,i] * (sign(x[b,i,p]) + bias[i]) )
__global__ __launch_bounds__(256) void conv_pre(const float* __restrict__ x,
                                                const float* __restrict__ bias,
                                                const float* __restrict__ Wp,
                                                u16* __restrict__ y1){
    int p   = blockIdx.x*256 + threadIdx.x;
    int b   = p >> 14;
    int pix = p & (HW-1);
    const float* xb = x + (size_t)b*CHW + pix;

    float s[64];
#pragma unroll
    for (int i = 0; i < 64; i++)
        s[i] = sgnf(xb[(size_t)i*HW]) + bias[i];

    u16* yb = y1 + (size_t)b*CHW + pix;
#pragma unroll 4
    for (int o = 0; o < 64; o++){
        float a0=0.f, a1=0.f, a2=0.f, a3=0.f;
#pragma unroll
        for (int q = 0; q < 16; q++){
            a0 = fmaf(Wp[o*64+4*q+0], s[4*q+0], a0);
            a1 = fmaf(Wp[o*64+4*q+1], s[4*q+1], a1);
            a2 = fmaf(Wp[o*64+4*q+2], s[4*q+2], a2);
            a3 = fmaf(Wp[o*64+4*q+3], s[4*q+3], a3);
        }
        yb[(size_t)o*HW] = f2bf((a0+a1) + (a2+a3));
    }
}

// ----------------------------------------------------------------- bnp ----
// Partial BN sums of a bf16 tensor. grid 512: c = bid&63, slice = bid>>6.
__global__ __launch_bounds__(256) void bnp(const u16* __restrict__ X,
                                           float2* __restrict__ part){
    int bid = blockIdx.x;
    int c   = bid & 63, sl = bid >> 6;
    int tid = threadIdx.x;
    const u16* base = X + (size_t)c*HW + sl*2048;
    float s = 0.f, q = 0.f;
#pragma unroll
    for (int b = 0; b < 8; b++){
        uint4 v = reinterpret_cast<const uint4*>(base + (size_t)b*CHW)[tid];
        u32 w[4] = {v.x, v.y, v.z, v.w};
#pragma unroll
        for (int k = 0; k < 4; k++){
            float f0 = __uint_as_float(w[k] << 16);
            float f1 = __uint_as_float(w[k] & 0xffff0000u);
            s += f0 + f1;
            q += f0*f0 + f1*f1;
        }
    }
    for (int off = 32; off > 0; off >>= 1){
        s += __shfl_down(s, off);
        q += __shfl_down(q, off);
    }
    __shared__ float2 wp[4];
    if ((tid & 63) == 0) wp[tid>>6] = make_float2(s, q);
    __syncthreads();
    if (tid == 0){
        float S = 0.f, Q = 0.f;
        for (int w = 0; w < 4; w++){ S += wp[w].x; Q += wp[w].y; }
        part[bid] = make_float2(S, Q);
    }
}

__device__ __forceinline__ void bn_combine(const float2* __restrict__ part,
                                           const float* __restrict__ gamma,
                                           const float* __restrict__ beta,
                                           float* scl, float* shl, int tid){
    if (tid < 64){
        float S = 0.f, Q = 0.f;
#pragma unroll
        for (int sl = 0; sl < 8; sl++){
            float2 v = part[sl*64 + tid];
            S += v.x; Q += v.y;
        }
        float mean = S * (1.f/(float)NPIX);
        float var  = fmaxf(Q * (1.f/(float)NPIX) - mean*mean, 0.f);
        float sc = gamma[tid] * rsqrtf(var + EPS_);
        scl[tid] = sc;
        shl[tid] = beta[tid] - mean*sc;
    }
}

// ---------------------------------------------------------------- kerk ----
// z2 = prelu(BN1(y1)) + mid_bias (in regs); ker[b,j,p] = sum_i M[i,j]*z2[i,p]
__global__ __launch_bounds__(256) void kerk(const u16* __restrict__ y1,
                                            const float2* __restrict__ part1,
                                            const float* __restrict__ gamma,
                                            const float* __restrict__ beta,
                                            const float* __restrict__ pa,
                                            const float* __restrict__ mb,
                                            const float* __restrict__ M,
                                            u16* __restrict__ ker){
    __shared__ float scl[64], shl[64], al[64], mbl[64];
    int tid = threadIdx.x;
    bn_combine(part1, gamma, beta, scl, shl, tid);
    if (tid < 64){ al[tid] = pa[tid]; mbl[tid] = mb[tid]; }
    __syncthreads();

    int p   = blockIdx.x*256 + tid;
    int b   = p >> 14;
    int pix = p & (HW-1);
    const u16* yb = y1 + (size_t)b*CHW + pix;

    float acc[9];
#pragma unroll
    for (int j = 0; j < 9; j++) acc[j] = 0.f;
    for (int i = 0; i < 64; i++){
        float u = bf2f(yb[(size_t)i*HW]);
        float w = fmaf(scl[i], u, shl[i]);
        float z = fmaxf(w, 0.f) + al[i]*fminf(w, 0.f) + mbl[i];
#pragma unroll
        for (int j = 0; j < 9; j++)
            acc[j] = fmaf(M[i*9+j], z, acc[j]);
    }
    u16* kb = ker + (size_t)b*9*HW + pix;
#pragma unroll
    for (int j = 0; j < 9; j++) kb[(size_t)j*HW] = f2bf(acc[j]);
}

// ------------------------------------------------------------- gatherk ----
// y2[b,c,p] = sum_j z2[b,c,p+off_j] * ker[b,j,p]
// block: 8 channels x 4 rows x 128 cols. z2 recomputed from y1 on the fly.
__global__ __launch_bounds__(256) void gatherk(const u16* __restrict__ y1,
                                               const float2* __restrict__ part1,
                                               const float* __restrict__ gamma,
                                               const float* __restrict__ beta,
                                               const float* __restrict__ pa,
                                               const float* __restrict__ mb,
                                               const u16* __restrict__ ker,
                                               u16* __restrict__ y2){
    __shared__ float scl[64], shl[64], al[64], mbl[64];
    __shared__ float zr[8*6*132];    // [cc][row 0..5][x 0..129(+2 pad)]  25.3KB

    int tid = threadIdx.x;
    bn_combine(part1, gamma, beta, scl, shl, tid);
    if (tid < 64){ al[tid] = pa[tid]; mbl[tid] = mb[tid]; }
    // zero x-halo columns
    if (tid < 96){
        int cc = tid / 12, rem = tid - cc*12, rr = rem >> 1, ed = rem & 1;
        zr[(cc*6 + rr)*132 + ed*129] = 0.f;
    }
    __syncthreads();

    int bid = blockIdx.x;
    int b  = bid >> 8;
    int cg = (bid >> 5) & 7;
    int rg = bid & 31;
    int y0 = rg*4;
    int c0 = cg*8;

    // load: 32-thread group per channel; 6 rows x 128 cols each; BN+prelu+mb
    {
        int cc   = tid >> 5;          // 0..7
        int lane = tid & 31;
        int c    = c0 + cc;
        float sc = scl[c], sh = shl[c], a = al[c], m = mbl[c];
        const u16* src = y1 + (size_t)(b*64 + c)*HW;
#pragma unroll
        for (int k = 0; k < 24; k++){
            int e  = lane + 32*k;     // 0..767
            int rr = e >> 7;          // 0..5
            int xx = e & 127;
            int gy = y0 + rr - 1;
            float z = 0.f;
            if ((unsigned)gy < 128u){
                float u = bf2f(src[gy*128 + xx]);
                float w = fmaf(sc, u, sh);
                z = fmaxf(w, 0.f) + a*fminf(w, 0.f) + m;
            }
            zr[(cc*6 + rr)*132 + xx + 1] = z;
        }
    }
    __syncthreads();

    // compute: lane owns 2 horizontal pixels; ker in registers
    {
        int lane2 = tid & 63;
        int ly    = tid >> 6;         // 0..3 (wave-uniform)
        int x0    = lane2*2;          // 0..126
        int gp    = (y0 + ly)*128 + x0;

        float k0[9], k1[9];
        const u16* kb = ker + (size_t)b*9*HW + gp;
#pragma unroll
        for (int j = 0; j < 9; j++){
            u32 u = *reinterpret_cast<const u32*>(kb + (size_t)j*HW);
            k0[j] = __uint_as_float(u << 16);
            k1[j] = __uint_as_float(u & 0xffff0000u);
        }

        u32* yo = reinterpret_cast<u32*>(y2 + (size_t)(b*64 + c0)*HW + gp);
#pragma unroll
        for (int cc = 0; cc < 8; cc++){
            const float* zrow = &zr[(cc*6 + ly)*132 + x0];
            float o0 = 0.f, o1 = 0.f;
#pragma unroll
            for (int dy = 0; dy < 3; dy++){
                float2 za = *reinterpret_cast<const float2*>(zrow + dy*132);
                float2 zb = *reinterpret_cast<const float2*>(zrow + dy*132 + 2);
                o0 = fmaf(za.x, k0[dy*3+0], o0);
                o0 = fmaf(za.y, k0[dy*3+1], o0);
                o0 = fmaf(zb.x, k0[dy*3+2], o0);
                o1 = fmaf(za.y, k1[dy*3+0], o1);
                o1 = fmaf(zb.x, k1[dy*3+1], o1);
                o1 = fmaf(zb.y, k1[dy*3+2], o1);
            }
            yo[(size_t)cc*(HW/2)] = pack2(o0, o1);
        }
    }
}

// ----------------------------------------------------------- conv_post ----
// y3 = f2bf( Wq * (relu(BN2(y2)) + post_bias) )
__global__ __launch_bounds__(256) void conv_post(const u16* __restrict__ y2,
                                                 const float2* __restrict__ part2,
                                                 const float* __restrict__ gamma,
                                                 const float* __restrict__ beta,
                                                 const float* __restrict__ pbias,
                                                 const float* __restrict__ Wq,
                                                 u16* __restrict__ y3){
    __shared__ float scl[64], shl[64];
    int tid = threadIdx.x;
    bn_combine(part2, gamma, beta, scl, shl, tid);
    __syncthreads();

    int p   = blockIdx.x*256 + tid;
    int b   = p >> 14;
    int pix = p & (HW-1);
    const u16* yb = y2 + (size_t)b*CHW + pix;

    float s[64];
#pragma unroll
    for (int i = 0; i < 64; i++){
        float u = fmaf(scl[i], bf2f(yb[(size_t)i*HW]), shl[i]);
        s[i] = fmaxf(u, 0.f) + pbias[i];
    }

    u16* ob = y3 + (size_t)b*CHW + pix;
#pragma unroll 4
    for (int o = 0; o < 64; o++){
        float a0=0.f, a1=0.f, a2=0.f, a3=0.f;
#pragma unroll
        for (int q = 0; q < 16; q++){
            a0 = fmaf(Wq[o*64+4*q+0], s[4*q+0], a0);
            a1 = fmaf(Wq[o*64+4*q+1], s[4*q+1], a1);
            a2 = fmaf(Wq[o*64+4*q+2], s[4*q+2], a2);
            a3 = fmaf(Wq[o*64+4*q+3], s[4*q+3], a3);
        }
        ob[(size_t)o*HW] = f2bf((a0+a1) + (a2+a3));
    }
}

// --------------------------------------------------------------- final ----
// out = BN3(y3) + x
__global__ __launch_bounds__(256) void finalk(const u16* __restrict__ y3,
                                              const float* __restrict__ x,
                                              const float2* __restrict__ part3,
                                              const float* __restrict__ gamma,
                                              const float* __restrict__ beta,
                                              float* __restrict__ out){
    __shared__ float scl[64], shl[64];
    int tid = threadIdx.x;
    bn_combine(part3, gamma, beta, scl, shl, tid);
    __syncthreads();
#pragma unroll
    for (int it = 0; it < 4; it++){
        int i4 = blockIdx.x*1024 + it*256 + tid;   // float4 / 4-pixel index
        int c  = (i4 >> 12) & 63;
        uint2  yv = reinterpret_cast<const uint2*>(y3)[i4];
        float4 bx = reinterpret_cast<const float4*>(x)[i4];
        float s = scl[c], t = shl[c];
        float4 r;
        r.x = fmaf(s, __uint_as_float(yv.x << 16),          t) + bx.x;
        r.y = fmaf(s, __uint_as_float(yv.x & 0xffff0000u),  t) + bx.y;
        r.z = fmaf(s, __uint_as_float(yv.y << 16),          t) + bx.z;
        r.w = fmaf(s, __uint_as_float(yv.y & 0xffff0000u),  t) + bx.w;
        reinterpret_cast<float4*>(out)[i4] = r;
    }
}

// -------------------------------------------------------------- launch ----
extern "C" void kernel_launch(void* const* d_in, const int* in_sizes, int n_in,
                              void* d_out, int out_size, void* d_ws, size_t ws_size,
                              hipStream_t stream){
    const float* x        = (const float*)d_in[0];
    const float* pre_bias = (const float*)d_in[1];
    const float* pre_w    = (const float*)d_in[2];
    const float* pre_g    = (const float*)d_in[3];
    const float* pre_b    = (const float*)d_in[4];
    const float* pre_a    = (const float*)d_in[5];
    const float* mid_bias = (const float*)d_in[6];
    const float* red_w    = (const float*)d_in[7];
    const float* span_w   = (const float*)d_in[8];
    const float* mid_g    = (const float*)d_in[9];
    const float* mid_b    = (const float*)d_in[10];
    const float* post_bias= (const float*)d_in[12];
    const float* post_w   = (const float*)d_in[13];
    const float* post_g   = (const float*)d_in[14];
    const float* post_b   = (const float*)d_in[15];

    float* ws   = (float*)d_ws;
    u16*   y1b  = (u16*)ws;                          // 8.4M bf16 (later y3b)
    u16*   kerb = (u16*)(ws + 4194304);              // 1.18M bf16
    float* Wp   = ws + 4194304 + 589824;             // 4096
    float* Wq   = Wp + 4096;                         // 4096
    float* M    = Wq + 4096;                         // 576 (pad 640)
    float2* part1 = (float2*)(M + 640);              // 512
    float2* part2 = part1 + 512;
    float2* part3 = part2 + 512;

    u16*   y2b = (u16*)d_out;                        // scratch (first 16.8MB)
    float* out = (float*)d_out;

    hipLaunchKernelGGL(prep, dim3(1), dim3(64), 0, stream,
                       pre_w, red_w, span_w, post_w, Wp, Wq, M);
    hipLaunchKernelGGL(conv_pre, dim3(NPIX/256), dim3(256), 0, stream,
                       x, pre_bias, Wp, y1b);
    hipLaunchKernelGGL(bnp, dim3(512), dim3(256), 0, stream, y1b, part1);
    hipLaunchKernelGGL(kerk, dim3(NPIX/256), dim3(256), 0, stream,
                       y1b, part1, pre_g, pre_b, pre_a, mid_bias, M, kerb);
    hipLaunchKernelGGL(gatherk, dim3(2048), dim3(256), 0, stream,
                       y1b, part1, pre_g, pre_b, pre_a, mid_bias, kerb, y2b);
    hipLaunchKernelGGL(bnp, dim3(512), dim3(256), 0, stream, y2b, part2);
    hipLaunchKernelGGL(conv_post, dim3(NPIX/256), dim3(256), 0, stream,
                       y2b, part2, mid_g, mid_b, post_bias, Wq, y1b);
    hipLaunchKernelGGL(bnp, dim3(512), dim3(256), 0, stream, y1b, part3);
    hipLaunchKernelGGL(finalk, dim3(2048), dim3(256), 0, stream,
                       y1b, x, part3, post_g, post_b, out);
}

// Round 4
// 128.429 us; speedup vs baseline: 1.6589x; 1.2807x over previous
//
#include <hip/hip_runtime.h>

#define B_   8
#define C_   64
#define HW   16384
#define CHW  (C_*HW)
#define NPIX (B_*HW)
#define EPS_ 1e-5f

typedef unsigned short u16;
typedef unsigned int   u32;

__device__ __forceinline__ float sgnf(float v){ return (float)((v>0.f)-(v<0.f)); }
__device__ __forceinline__ float bf2f(u16 h){ return __uint_as_float(((u32)h)<<16); }
__device__ __forceinline__ u16 f2bf(float f){
    u32 u = __float_as_uint(f);
    u += 0x7fffu + ((u>>16)&1u);
    return (u16)(u>>16);
}
__device__ __forceinline__ u32 pack2(float a, float b){
    return (u32)f2bf(a) | ((u32)f2bf(b)<<16);
}

// ---------------------------------------------------------------- prep ----
// wb[2o],wb[2o+1]: sign bits of pre_w row o. AB[o] = -2*alpha_o,
// AB[64+o] = 64*alpha_o + dot(W_o, pre_bias). Wq: post binarized f32.
// M[i*9+j]: collapsed reduce+span.
__global__ void prep(const float* __restrict__ pre_w, const float* __restrict__ pre_bias,
                     const float* __restrict__ red_w, const float* __restrict__ span_w,
                     const float* __restrict__ post_w,
                     u32* __restrict__ wb, float* __restrict__ AB,
                     float* __restrict__ Wq, float* __restrict__ M){
    __shared__ float sr[32], ss[9];
    int t = threadIdx.x;
    if (t < 64){
        float s = 0.f;
        for (int i = 0; i < 64; i++) s += fabsf(pre_w[t*64+i]);
        float alpha = s * (1.f/64.f);
        u32 b0 = 0, b1 = 0;
        float c0 = 0.f;
        for (int i = 0; i < 32; i++){
            b0 |= (__float_as_uint(pre_w[t*64+i]) >> 31) << i;
            b1 |= (__float_as_uint(pre_w[t*64+32+i]) >> 31) << i;
        }
        for (int i = 0; i < 64; i++)
            c0 += alpha * sgnf(pre_w[t*64+i]) * pre_bias[i];
        wb[2*t]   = b0;
        wb[2*t+1] = b1;
        AB[t]     = -2.f * alpha;
        AB[64+t]  = 64.f * alpha + c0;

        float s2 = 0.f;
        for (int i = 0; i < 64; i++) s2 += fabsf(post_w[t*64+i]);
        s2 *= (1.f/64.f);
        for (int i = 0; i < 64; i++) Wq[t*64+i] = s2 * sgnf(post_w[t*64+i]);
    }
    if (t < 32){
        float s = 0.f;
        for (int i = 0; i < 64; i++) s += fabsf(red_w[t*64+i]);
        sr[t] = s * (1.f/64.f);
    }
    if (t < 9){
        float s = 0.f;
        for (int r = 0; r < 32; r++) s += fabsf(span_w[t*32+r]);
        ss[t] = s * (1.f/32.f);
    }
    __syncthreads();
    if (t < 64){
        for (int j = 0; j < 9; j++){
            float m = 0.f;
            for (int r = 0; r < 32; r++)
                m += sgnf(span_w[j*32+r]) * sr[r] * sgnf(red_w[r*64+t]);
            M[t*9+j] = ss[j] * m;
        }
    }
}

// ------------------------------------------------------------ conv_pre ----
// Binary GEMM: pack sign bits of x, y1[o,p] = fma(A_o, popc(wb_o ^ sb), B_o)
__global__ __launch_bounds__(256) void conv_pre(const float* __restrict__ x,
                                                const u32* __restrict__ wb,
                                                const float* __restrict__ AB,
                                                u16* __restrict__ y1){
    int p   = blockIdx.x*256 + threadIdx.x;
    int b   = p >> 14;
    int pix = p & (HW-1);
    const float* xb = x + (size_t)b*CHW + pix;

    u32 m0 = 0, m1 = 0;
#pragma unroll
    for (int i = 0; i < 32; i++)
        m0 |= (__float_as_uint(xb[(size_t)i*HW]) >> 31) << i;
#pragma unroll
    for (int i = 0; i < 32; i++)
        m1 |= (__float_as_uint(xb[(size_t)(32+i)*HW]) >> 31) << i;

    u16* yb = y1 + (size_t)b*CHW + pix;
#pragma unroll 8
    for (int o = 0; o < 64; o++){
        u32 e0 = m0 ^ wb[2*o];
        u32 e1 = m1 ^ wb[2*o+1];
        float pc = (float)(__popc(e0) + __popc(e1));
        yb[(size_t)o*HW] = f2bf(fmaf(AB[o], pc, AB[64+o]));
    }
}

// ----------------------------------------------------------------- bnp ----
__global__ __launch_bounds__(256) void bnp(const u16* __restrict__ X,
                                           float2* __restrict__ part){
    int bid = blockIdx.x;
    int c   = bid & 63, sl = bid >> 6;
    int tid = threadIdx.x;
    const u16* base = X + (size_t)c*HW + sl*2048;
    float s = 0.f, q = 0.f;
#pragma unroll
    for (int b = 0; b < 8; b++){
        uint4 v = reinterpret_cast<const uint4*>(base + (size_t)b*CHW)[tid];
        u32 w[4] = {v.x, v.y, v.z, v.w};
#pragma unroll
        for (int k = 0; k < 4; k++){
            float f0 = __uint_as_float(w[k] << 16);
            float f1 = __uint_as_float(w[k] & 0xffff0000u);
            s += f0 + f1;
            q += f0*f0 + f1*f1;
        }
    }
    for (int off = 32; off > 0; off >>= 1){
        s += __shfl_down(s, off);
        q += __shfl_down(q, off);
    }
    __shared__ float2 wp[4];
    if ((tid & 63) == 0) wp[tid>>6] = make_float2(s, q);
    __syncthreads();
    if (tid == 0){
        float S = 0.f, Q = 0.f;
        for (int w = 0; w < 4; w++){ S += wp[w].x; Q += wp[w].y; }
        part[bid] = make_float2(S, Q);
    }
}

__device__ __forceinline__ void bn_combine(const float2* __restrict__ part,
                                           const float* __restrict__ gamma,
                                           const float* __restrict__ beta,
                                           float* scl, float* shl, int tid){
    if (tid < 64){
        float S = 0.f, Q = 0.f;
#pragma unroll
        for (int sl = 0; sl < 8; sl++){
            float2 v = part[sl*64 + tid];
            S += v.x; Q += v.y;
        }
        float mean = S * (1.f/(float)NPIX);
        float var  = fmaxf(Q * (1.f/(float)NPIX) - mean*mean, 0.f);
        float sc = gamma[tid] * rsqrtf(var + EPS_);
        scl[tid] = sc;
        shl[tid] = beta[tid] - mean*sc;
    }
}

// ---------------------------------------------------------------- kerk ----
__global__ __launch_bounds__(256) void kerk(const u16* __restrict__ y1,
                                            const float2* __restrict__ part1,
                                            const float* __restrict__ gamma,
                                            const float* __restrict__ beta,
                                            const float* __restrict__ pa,
                                            const float* __restrict__ mb,
                                            const float* __restrict__ M,
                                            u16* __restrict__ ker){
    __shared__ float scl[64], shl[64], al[64], mbl[64];
    int tid = threadIdx.x;
    bn_combine(part1, gamma, beta, scl, shl, tid);
    if (tid < 64){ al[tid] = pa[tid]; mbl[tid] = mb[tid]; }
    __syncthreads();

    int p   = blockIdx.x*256 + tid;
    int b   = p >> 14;
    int pix = p & (HW-1);
    const u16* yb = y1 + (size_t)b*CHW + pix;

    float acc[9];
#pragma unroll
    for (int j = 0; j < 9; j++) acc[j] = 0.f;
    for (int i = 0; i < 64; i++){
        float u = bf2f(yb[(size_t)i*HW]);
        float w = fmaf(scl[i], u, shl[i]);
        float z = fmaxf(w, 0.f) + al[i]*fminf(w, 0.f) + mbl[i];
#pragma unroll
        for (int j = 0; j < 9; j++)
            acc[j] = fmaf(M[i*9+j], z, acc[j]);
    }
    u16* kb = ker + (size_t)b*9*HW + pix;
#pragma unroll
    for (int j = 0; j < 9; j++) kb[(size_t)j*HW] = f2bf(acc[j]);
}

// ------------------------------------------------------------- gatherk ----
__global__ __launch_bounds__(256) void gatherk(const u16* __restrict__ y1,
                                               const float2* __restrict__ part1,
                                               const float* __restrict__ gamma,
                                               const float* __restrict__ beta,
                                               const float* __restrict__ pa,
                                               const float* __restrict__ mb,
                                               const u16* __restrict__ ker,
                                               u16* __restrict__ y2){
    __shared__ float scl[64], shl[64], al[64], mbl[64];
    __shared__ float zr[8*6*132];    // 25.3KB

    int tid = threadIdx.x;
    bn_combine(part1, gamma, beta, scl, shl, tid);
    if (tid < 64){ al[tid] = pa[tid]; mbl[tid] = mb[tid]; }
    if (tid < 96){
        int cc = tid / 12, rem = tid - cc*12, rr = rem >> 1, ed = rem & 1;
        zr[(cc*6 + rr)*132 + ed*129] = 0.f;
    }
    __syncthreads();

    int bid = blockIdx.x;
    int b  = bid >> 8;
    int cg = (bid >> 5) & 7;
    int rg = bid & 31;
    int y0 = rg*4;
    int c0 = cg*8;

    {
        int cc   = tid >> 5;
        int lane = tid & 31;
        int c    = c0 + cc;
        float sc = scl[c], sh = shl[c], a = al[c], m = mbl[c];
        const u16* src = y1 + (size_t)(b*64 + c)*HW;
#pragma unroll
        for (int k = 0; k < 24; k++){
            int e  = lane + 32*k;
            int rr = e >> 7;
            int xx = e & 127;
            int gy = y0 + rr - 1;
            float z = 0.f;
            if ((unsigned)gy < 128u){
                float u = bf2f(src[gy*128 + xx]);
                float w = fmaf(sc, u, sh);
                z = fmaxf(w, 0.f) + a*fminf(w, 0.f) + m;
            }
            zr[(cc*6 + rr)*132 + xx + 1] = z;
        }
    }
    __syncthreads();

    {
        int lane2 = tid & 63;
        int ly    = tid >> 6;
        int x0    = lane2*2;
        int gp    = (y0 + ly)*128 + x0;

        float k0[9], k1[9];
        const u16* kb = ker + (size_t)b*9*HW + gp;
#pragma unroll
        for (int j = 0; j < 9; j++){
            u32 u = *reinterpret_cast<const u32*>(kb + (size_t)j*HW);
            k0[j] = __uint_as_float(u << 16);
            k1[j] = __uint_as_float(u & 0xffff0000u);
        }

        u32* yo = reinterpret_cast<u32*>(y2 + (size_t)(b*64 + c0)*HW + gp);
#pragma unroll
        for (int cc = 0; cc < 8; cc++){
            const float* zrow = &zr[(cc*6 + ly)*132 + x0];
            float o0 = 0.f, o1 = 0.f;
#pragma unroll
            for (int dy = 0; dy < 3; dy++){
                float2 za = *reinterpret_cast<const float2*>(zrow + dy*132);
                float2 zb = *reinterpret_cast<const float2*>(zrow + dy*132 + 2);
                o0 = fmaf(za.x, k0[dy*3+0], o0);
                o0 = fmaf(za.y, k0[dy*3+1], o0);
                o0 = fmaf(zb.x, k0[dy*3+2], o0);
                o1 = fmaf(za.y, k1[dy*3+0], o1);
                o1 = fmaf(zb.x, k1[dy*3+1], o1);
                o1 = fmaf(zb.y, k1[dy*3+2], o1);
            }
            yo[(size_t)cc*(HW/2)] = pack2(o0, o1);
        }
    }
}

// ----------------------------------------------------------- conv_post ----
// Split o into 4 groups of 16 (fast-varying grid dim -> same-pixel blocks
// adjacent -> co-resident -> L2 reuse). 2048 blocks = 32 waves/CU.
__global__ __launch_bounds__(256) void conv_post(const u16* __restrict__ y2,
                                                 const float2* __restrict__ part2,
                                                 const float* __restrict__ gamma,
                                                 const float* __restrict__ beta,
                                                 const float* __restrict__ pbias,
                                                 const float* __restrict__ Wq,
                                                 u16* __restrict__ y3){
    __shared__ float scl[64], shl[64];
    int tid = threadIdx.x;
    bn_combine(part2, gamma, beta, scl, shl, tid);
    __syncthreads();

    int bid = blockIdx.x;
    int og  = bid & 3;
    int o0  = og*16;
    int p   = (bid >> 2)*256 + tid;
    int b   = p >> 14;
    int pix = p & (HW-1);
    const u16* yb = y2 + (size_t)b*CHW + pix;

    float s[64];
#pragma unroll
    for (int i = 0; i < 64; i++){
        float u = fmaf(scl[i], bf2f(yb[(size_t)i*HW]), shl[i]);
        s[i] = fmaxf(u, 0.f) + pbias[i];
    }

    u16* ob = y3 + (size_t)b*CHW + pix;
#pragma unroll 4
    for (int oo = 0; oo < 16; oo++){
        int o = o0 + oo;
        float a0=0.f, a1=0.f, a2=0.f, a3=0.f;
#pragma unroll
        for (int q = 0; q < 16; q++){
            a0 = fmaf(Wq[o*64+4*q+0], s[4*q+0], a0);
            a1 = fmaf(Wq[o*64+4*q+1], s[4*q+1], a1);
            a2 = fmaf(Wq[o*64+4*q+2], s[4*q+2], a2);
            a3 = fmaf(Wq[o*64+4*q+3], s[4*q+3], a3);
        }
        ob[(size_t)o*HW] = f2bf((a0+a1) + (a2+a3));
    }
}

// --------------------------------------------------------------- final ----
__global__ __launch_bounds__(256) void finalk(const u16* __restrict__ y3,
                                              const float* __restrict__ x,
                                              const float2* __restrict__ part3,
                                              const float* __restrict__ gamma,
                                              const float* __restrict__ beta,
                                              float* __restrict__ out){
    __shared__ float scl[64], shl[64];
    int tid = threadIdx.x;
    bn_combine(part3, gamma, beta, scl, shl, tid);
    __syncthreads();
#pragma unroll
    for (int it = 0; it < 4; it++){
        int i4 = blockIdx.x*1024 + it*256 + tid;
        int c  = (i4 >> 12) & 63;
        uint2  yv = reinterpret_cast<const uint2*>(y3)[i4];
        float4 bx = reinterpret_cast<const float4*>(x)[i4];
        float s = scl[c], t = shl[c];
        float4 r;
        r.x = fmaf(s, __uint_as_float(yv.x << 16),          t) + bx.x;
        r.y = fmaf(s, __uint_as_float(yv.x & 0xffff0000u),  t) + bx.y;
        r.z = fmaf(s, __uint_as_float(yv.y << 16),          t) + bx.z;
        r.w = fmaf(s, __uint_as_float(yv.y & 0xffff0000u),  t) + bx.w;
        reinterpret_cast<float4*>(out)[i4] = r;
    }
}

// -------------------------------------------------------------- launch ----
extern "C" void kernel_launch(void* const* d_in, const int* in_sizes, int n_in,
                              void* d_out, int out_size, void* d_ws, size_t ws_size,
                              hipStream_t stream){
    const float* x        = (const float*)d_in[0];
    const float* pre_bias = (const float*)d_in[1];
    const float* pre_w    = (const float*)d_in[2];
    const float* pre_g    = (const float*)d_in[3];
    const float* pre_b    = (const float*)d_in[4];
    const float* pre_a    = (const float*)d_in[5];
    const float* mid_bias = (const float*)d_in[6];
    const float* red_w    = (const float*)d_in[7];
    const float* span_w   = (const float*)d_in[8];
    const float* mid_g    = (const float*)d_in[9];
    const float* mid_b    = (const float*)d_in[10];
    const float* post_bias= (const float*)d_in[12];
    const float* post_w   = (const float*)d_in[13];
    const float* post_g   = (const float*)d_in[14];
    const float* post_b   = (const float*)d_in[15];

    float* ws   = (float*)d_ws;
    u16*   y1b  = (u16*)ws;                          // 8.4M bf16 (later y3b)
    u16*   kerb = (u16*)(ws + 4194304);              // 1.18M bf16
    float* Wq   = ws + 4194304 + 589824;             // 4096
    float* M    = Wq + 4096;                         // 576 (pad 640)
    u32*   wb   = (u32*)(M + 640);                   // 128
    float* AB   = (float*)(wb + 128);                // 128
    float2* part1 = (float2*)(AB + 128);             // 512
    float2* part2 = part1 + 512;
    float2* part3 = part2 + 512;

    u16*   y2b = (u16*)d_out;
    float* out = (float*)d_out;

    hipLaunchKernelGGL(prep, dim3(1), dim3(64), 0, stream,
                       pre_w, pre_bias, red_w, span_w, post_w, wb, AB, Wq, M);
    hipLaunchKernelGGL(conv_pre, dim3(NPIX/256), dim3(256), 0, stream,
                       x, wb, AB, y1b);
    hipLaunchKernelGGL(bnp, dim3(512), dim3(256), 0, stream, y1b, part1);
    hipLaunchKernelGGL(kerk, dim3(NPIX/256), dim3(256), 0, stream,
                       y1b, part1, pre_g, pre_b, pre_a, mid_bias, M, kerb);
    hipLaunchKernelGGL(gatherk, dim3(2048), dim3(256), 0, stream,
                       y1b, part1, pre_g, pre_b, pre_a, mid_bias, kerb, y2b);
    hipLaunchKernelGGL(bnp, dim3(512), dim3(256), 0, stream, y2b, part2);
    hipLaunchKernelGGL(conv_post, dim3(2048), dim3(256), 0, stream,
                       y2b, part2, mid_g, mid_b, post_bias, Wq, y1b);
    hipLaunchKernelGGL(bnp, dim3(512), dim3(256), 0, stream, y1b, part3);
    hipLaunchKernelGGL(finalk, dim3(2048), dim3(256), 0, stream,
                       y1b, x, part3, post_g, post_b, out);
}

// Round 5
// 104.580 us; speedup vs baseline: 2.0372x; 1.2280x over previous
//
#include <hip/hip_runtime.h>

#define B_   8
#define C_   64
#define HW   16384
#define CHW  (C_*HW)
#define NPIX (B_*HW)
#define EPS_ 1e-5f

typedef unsigned short u16;
typedef unsigned int   u32;
typedef __attribute__((ext_vector_type(8))) short bf16x8;
typedef __attribute__((ext_vector_type(4))) float f32x4;

__device__ __forceinline__ float sgnf(float v){ return (float)((v>0.f)-(v<0.f)); }
__device__ __forceinline__ float bf2f(u16 h){ return __uint_as_float(((u32)h)<<16); }
__device__ __forceinline__ u16 f2bf(float f){
    u32 u = __float_as_uint(f);
    u += 0x7fffu + ((u>>16)&1u);
    return (u16)(u>>16);
}
__device__ __forceinline__ u32 pack2(float a, float b){
    return (u32)f2bf(a) | ((u32)f2bf(b)<<16);
}

// ---------------------------------------------------------------- prep ----
__global__ void prep(const float* __restrict__ pre_w, const float* __restrict__ pre_bias,
                     const float* __restrict__ red_w, const float* __restrict__ span_w,
                     const float* __restrict__ post_w,
                     u32* __restrict__ wb, float* __restrict__ AB,
                     float* __restrict__ Wq, float* __restrict__ M){
    __shared__ float sr[32], ss[9];
    int t = threadIdx.x;
    if (t < 64){
        float s = 0.f;
        for (int i = 0; i < 64; i++) s += fabsf(pre_w[t*64+i]);
        float alpha = s * (1.f/64.f);
        u32 b0 = 0, b1 = 0;
        float c0 = 0.f;
        for (int i = 0; i < 32; i++){
            b0 |= (__float_as_uint(pre_w[t*64+i]) >> 31) << i;
            b1 |= (__float_as_uint(pre_w[t*64+32+i]) >> 31) << i;
        }
        for (int i = 0; i < 64; i++)
            c0 += alpha * sgnf(pre_w[t*64+i]) * pre_bias[i];
        wb[2*t]   = b0;
        wb[2*t+1] = b1;
        AB[t]     = -2.f * alpha;
        AB[64+t]  = 64.f * alpha + c0;

        float s2 = 0.f;
        for (int i = 0; i < 64; i++) s2 += fabsf(post_w[t*64+i]);
        s2 *= (1.f/64.f);
        for (int i = 0; i < 64; i++) Wq[t*64+i] = s2 * sgnf(post_w[t*64+i]);
    }
    if (t < 32){
        float s = 0.f;
        for (int i = 0; i < 64; i++) s += fabsf(red_w[t*64+i]);
        sr[t] = s * (1.f/64.f);
    }
    if (t < 9){
        float s = 0.f;
        for (int r = 0; r < 32; r++) s += fabsf(span_w[t*32+r]);
        ss[t] = s * (1.f/32.f);
    }
    __syncthreads();
    if (t < 64){
        for (int j = 0; j < 9; j++){
            float m = 0.f;
            for (int r = 0; r < 32; r++)
                m += sgnf(span_w[j*32+r]) * sr[r] * sgnf(red_w[r*64+t]);
            M[t*9+j] = ss[j] * m;
        }
    }
}

// ------------------------------------------------------------ conv_pre ----
__global__ __launch_bounds__(256) void conv_pre(const float* __restrict__ x,
                                                const u32* __restrict__ wb,
                                                const float* __restrict__ AB,
                                                u16* __restrict__ y1){
    int p   = blockIdx.x*256 + threadIdx.x;
    int b   = p >> 14;
    int pix = p & (HW-1);
    const float* xb = x + (size_t)b*CHW + pix;

    u32 m0 = 0, m1 = 0;
#pragma unroll
    for (int i = 0; i < 32; i++)
        m0 |= (__float_as_uint(xb[(size_t)i*HW]) >> 31) << i;
#pragma unroll
    for (int i = 0; i < 32; i++)
        m1 |= (__float_as_uint(xb[(size_t)(32+i)*HW]) >> 31) << i;

    u16* yb = y1 + (size_t)b*CHW + pix;
#pragma unroll 8
    for (int o = 0; o < 64; o++){
        u32 e0 = m0 ^ wb[2*o];
        u32 e1 = m1 ^ wb[2*o+1];
        float pc = (float)(__popc(e0) + __popc(e1));
        yb[(size_t)o*HW] = f2bf(fmaf(AB[o], pc, AB[64+o]));
    }
}

// ----------------------------------------------------------------- bnp ----
__global__ __launch_bounds__(256) void bnp(const u16* __restrict__ X,
                                           float2* __restrict__ part){
    int bid = blockIdx.x;
    int c   = bid & 63, sl = bid >> 6;
    int tid = threadIdx.x;
    const u16* base = X + (size_t)c*HW + sl*2048;
    float s = 0.f, q = 0.f;
#pragma unroll
    for (int b = 0; b < 8; b++){
        uint4 v = reinterpret_cast<const uint4*>(base + (size_t)b*CHW)[tid];
        u32 w[4] = {v.x, v.y, v.z, v.w};
#pragma unroll
        for (int k = 0; k < 4; k++){
            float f0 = __uint_as_float(w[k] << 16);
            float f1 = __uint_as_float(w[k] & 0xffff0000u);
            s += f0 + f1;
            q += f0*f0 + f1*f1;
        }
    }
    for (int off = 32; off > 0; off >>= 1){
        s += __shfl_down(s, off);
        q += __shfl_down(q, off);
    }
    __shared__ float2 wp[4];
    if ((tid & 63) == 0) wp[tid>>6] = make_float2(s, q);
    __syncthreads();
    if (tid == 0){
        float S = 0.f, Q = 0.f;
        for (int w = 0; w < 4; w++){ S += wp[w].x; Q += wp[w].y; }
        part[bid] = make_float2(S, Q);
    }
}

__device__ __forceinline__ void bn_combine(const float2* __restrict__ part,
                                           const float* __restrict__ gamma,
                                           const float* __restrict__ beta,
                                           float* scl, float* shl, int tid){
    if (tid < 64){
        float S = 0.f, Q = 0.f;
#pragma unroll
        for (int sl = 0; sl < 8; sl++){
            float2 v = part[sl*64 + tid];
            S += v.x; Q += v.y;
        }
        float mean = S * (1.f/(float)NPIX);
        float var  = fmaxf(Q * (1.f/(float)NPIX) - mean*mean, 0.f);
        float sc = gamma[tid] * rsqrtf(var + EPS_);
        scl[tid] = sc;
        shl[tid] = beta[tid] - mean*sc;
    }
}

// ---------------------------------------------------------------- kerk ----
__global__ __launch_bounds__(256) void kerk(const u16* __restrict__ y1,
                                            const float2* __restrict__ part1,
                                            const float* __restrict__ gamma,
                                            const float* __restrict__ beta,
                                            const float* __restrict__ pa,
                                            const float* __restrict__ mb,
                                            const float* __restrict__ M,
                                            u16* __restrict__ ker){
    __shared__ float scl[64], shl[64], al[64], mbl[64];
    int tid = threadIdx.x;
    bn_combine(part1, gamma, beta, scl, shl, tid);
    if (tid < 64){ al[tid] = pa[tid]; mbl[tid] = mb[tid]; }
    __syncthreads();

    int p   = blockIdx.x*256 + tid;
    int b   = p >> 14;
    int pix = p & (HW-1);
    const u16* yb = y1 + (size_t)b*CHW + pix;

    float acc[9];
#pragma unroll
    for (int j = 0; j < 9; j++) acc[j] = 0.f;
    for (int i = 0; i < 64; i++){
        float u = bf2f(yb[(size_t)i*HW]);
        float w = fmaf(scl[i], u, shl[i]);
        float z = fmaxf(w, 0.f) + al[i]*fminf(w, 0.f) + mbl[i];
#pragma unroll
        for (int j = 0; j < 9; j++)
            acc[j] = fmaf(M[i*9+j], z, acc[j]);
    }
    u16* kb = ker + (size_t)b*9*HW + pix;
#pragma unroll
    for (int j = 0; j < 9; j++) kb[(size_t)j*HW] = f2bf(acc[j]);
}

// ------------------------------------------------------------- gatherk ----
__global__ __launch_bounds__(256) void gatherk(const u16* __restrict__ y1,
                                               const float2* __restrict__ part1,
                                               const float* __restrict__ gamma,
                                               const float* __restrict__ beta,
                                               const float* __restrict__ pa,
                                               const float* __restrict__ mb,
                                               const u16* __restrict__ ker,
                                               u16* __restrict__ y2){
    __shared__ float scl[64], shl[64], al[64], mbl[64];
    __shared__ float zr[8*6*132];    // 25.3KB

    int tid = threadIdx.x;
    bn_combine(part1, gamma, beta, scl, shl, tid);
    if (tid < 64){ al[tid] = pa[tid]; mbl[tid] = mb[tid]; }
    if (tid < 96){
        int cc = tid / 12, rem = tid - cc*12, rr = rem >> 1, ed = rem & 1;
        zr[(cc*6 + rr)*132 + ed*129] = 0.f;
    }
    __syncthreads();

    int bid = blockIdx.x;
    int b  = bid >> 8;
    int cg = (bid >> 5) & 7;
    int rg = bid & 31;
    int y0 = rg*4;
    int c0 = cg*8;

    {
        int cc   = tid >> 5;
        int lane = tid & 31;
        int c    = c0 + cc;
        float sc = scl[c], sh = shl[c], a = al[c], m = mbl[c];
        const u16* src = y1 + (size_t)(b*64 + c)*HW;
#pragma unroll
        for (int k = 0; k < 24; k++){
            int e  = lane + 32*k;
            int rr = e >> 7;
            int xx = e & 127;
            int gy = y0 + rr - 1;
            float z = 0.f;
            if ((unsigned)gy < 128u){
                float u = bf2f(src[gy*128 + xx]);
                float w = fmaf(sc, u, sh);
                z = fmaxf(w, 0.f) + a*fminf(w, 0.f) + m;
            }
            zr[(cc*6 + rr)*132 + xx + 1] = z;
        }
    }
    __syncthreads();

    {
        int lane2 = tid & 63;
        int ly    = tid >> 6;
        int x0    = lane2*2;
        int gp    = (y0 + ly)*128 + x0;

        float k0[9], k1[9];
        const u16* kb = ker + (size_t)b*9*HW + gp;
#pragma unroll
        for (int j = 0; j < 9; j++){
            u32 u = *reinterpret_cast<const u32*>(kb + (size_t)j*HW);
            k0[j] = __uint_as_float(u << 16);
            k1[j] = __uint_as_float(u & 0xffff0000u);
        }

        u32* yo = reinterpret_cast<u32*>(y2 + (size_t)(b*64 + c0)*HW + gp);
#pragma unroll
        for (int cc = 0; cc < 8; cc++){
            const float* zrow = &zr[(cc*6 + ly)*132 + x0];
            float o0 = 0.f, o1 = 0.f;
#pragma unroll
            for (int dy = 0; dy < 3; dy++){
                float2 za = *reinterpret_cast<const float2*>(zrow + dy*132);
                float2 zb = *reinterpret_cast<const float2*>(zrow + dy*132 + 2);
                o0 = fmaf(za.x, k0[dy*3+0], o0);
                o0 = fmaf(za.y, k0[dy*3+1], o0);
                o0 = fmaf(zb.x, k0[dy*3+2], o0);
                o1 = fmaf(za.y, k1[dy*3+0], o1);
                o1 = fmaf(zb.x, k1[dy*3+1], o1);
                o1 = fmaf(zb.y, k1[dy*3+2], o1);
            }
            yo[(size_t)cc*(HW/2)] = pack2(o0, o1);
        }
    }
}

// ----------------------------------------------------------- conv_post ----
// MFMA bf16 GEMM: y3[o,p] = Wq[o,:] . s[:,p], s = relu(BN2(y2)) + post_bias.
// Block: 256 px, all 64 o. LDS: sB[px][k] (XOR-swizzled 8-blocks), sA[o][k].
// Wave w: px quarter w*64..w*64+63, 4 o-stripes x 4 px-subtiles x K=64.
__global__ __launch_bounds__(256) void conv_post(const u16* __restrict__ y2,
                                                 const float2* __restrict__ part2,
                                                 const float* __restrict__ gamma,
                                                 const float* __restrict__ beta,
                                                 const float* __restrict__ pbias,
                                                 const float* __restrict__ Wq,
                                                 u16* __restrict__ y3){
    __shared__ u16 sB[256*64];     // 32 KB
    __shared__ u16 sA[64*64];      //  8 KB
    __shared__ float scl[64], shl[64], pbl[64];

    int tid = threadIdx.x;
    bn_combine(part2, gamma, beta, scl, shl, tid);
    if (tid < 64) pbl[tid] = pbias[tid];

    // stage A (no scl dependency): thread t -> o = t>>2, 16 k from (t&3)*16
    {
        int o  = tid >> 2;
        int k0 = (tid & 3) << 4;
        const float* wr = Wq + o*64 + k0;
        int swz = (o & 7) << 3;
#pragma unroll
        for (int s8 = 0; s8 < 2; s8++){
            uint4 q;
            q.x = pack2(wr[s8*8+0], wr[s8*8+1]);
            q.y = pack2(wr[s8*8+2], wr[s8*8+3]);
            q.z = pack2(wr[s8*8+4], wr[s8*8+5]);
            q.w = pack2(wr[s8*8+6], wr[s8*8+7]);
            *reinterpret_cast<uint4*>(&sA[o*64 + ((k0 + s8*8) ^ swz)]) = q;
        }
    }
    __syncthreads();   // scl/shl/pbl ready

    int b    = blockIdx.x >> 6;
    int pix0 = (blockIdx.x & 63) << 8;

    // stage B: thread t -> channel pair cp = t&31, octet group g = t>>5
    {
        int cp = tid & 31;
        int g  = tid >> 5;
        const u16* r0 = y2 + (size_t)(b*64 + 2*cp)*HW + pix0;
        const u16* r1 = r0 + HW;
        float s0 = scl[2*cp],   h0 = shl[2*cp],   p0 = pbl[2*cp];
        float s1 = scl[2*cp+1], h1 = shl[2*cp+1], p1 = pbl[2*cp+1];
#pragma unroll
        for (int it = 0; it < 4; it++){
            int oct = g + it*8;                  // 0..31, 8 px each
            uint4 va = *reinterpret_cast<const uint4*>(r0 + oct*8);
            uint4 vb = *reinterpret_cast<const uint4*>(r1 + oct*8);
            u32 wa[4] = {va.x, va.y, va.z, va.w};
            u32 wc[4] = {vb.x, vb.y, vb.z, vb.w};
#pragma unroll
            for (int k = 0; k < 4; k++){
                int px = oct*8 + 2*k;
                float a0 = fmaf(s0, bf2f((u16)(wa[k] & 0xffffu)), h0);
                float a1 = fmaf(s0, bf2f((u16)(wa[k] >> 16)),     h0);
                float c0v= fmaf(s1, bf2f((u16)(wc[k] & 0xffffu)), h1);
                float c1v= fmaf(s1, bf2f((u16)(wc[k] >> 16)),     h1);
                a0 = fmaxf(a0, 0.f) + p0;  a1 = fmaxf(a1, 0.f) + p0;
                c0v= fmaxf(c0v,0.f) + p1;  c1v= fmaxf(c1v,0.f) + p1;
                int e0 = px*64     + ((2*cp) ^ ((px & 7) << 3));
                int e1 = (px+1)*64 + ((2*cp) ^ (((px+1) & 7) << 3));
                *reinterpret_cast<u32*>(&sB[e0]) = pack2(a0, c0v);
                *reinterpret_cast<u32*>(&sB[e1]) = pack2(a1, c1v);
            }
        }
    }
    __syncthreads();

    // MFMA
    int w  = tid >> 6;
    int l  = tid & 63;
    int lr = l & 15;
    int lk = l >> 4;

    bf16x8 af[4][2];
#pragma unroll
    for (int os = 0; os < 4; os++){
        int o = os*16 + lr;
        int swz = (o & 7) << 3;
#pragma unroll
        for (int kf = 0; kf < 2; kf++){
            int k8 = lk*8 + kf*32;
            af[os][kf] = *reinterpret_cast<const bf16x8*>(&sA[o*64 + (k8 ^ swz)]);
        }
    }

    f32x4 acc[4][4];
#pragma unroll
    for (int os = 0; os < 4; os++)
#pragma unroll
        for (int ns = 0; ns < 4; ns++)
            acc[os][ns] = (f32x4){0.f, 0.f, 0.f, 0.f};

#pragma unroll
    for (int ns = 0; ns < 4; ns++){
        int px  = w*64 + ns*16 + lr;
        int swz = (px & 7) << 3;
        bf16x8 b0 = *reinterpret_cast<const bf16x8*>(&sB[px*64 + ((lk*8)      ^ swz)]);
        bf16x8 b1 = *reinterpret_cast<const bf16x8*>(&sB[px*64 + ((lk*8 + 32) ^ swz)]);
#pragma unroll
        for (int os = 0; os < 4; os++){
            acc[os][ns] = __builtin_amdgcn_mfma_f32_16x16x32_bf16(af[os][0], b0, acc[os][ns], 0, 0, 0);
            acc[os][ns] = __builtin_amdgcn_mfma_f32_16x16x32_bf16(af[os][1], b1, acc[os][ns], 0, 0, 0);
        }
    }

    // epilogue: o = os*16 + lk*4 + reg, px = w*64 + ns*16 + lr
    u16* yb = y3 + (size_t)(b*64)*HW + pix0;
#pragma unroll
    for (int os = 0; os < 4; os++){
#pragma unroll
        for (int ns = 0; ns < 4; ns++){
            int px = w*64 + ns*16 + lr;
#pragma unroll
            for (int r = 0; r < 4; r++){
                int o = os*16 + lk*4 + r;
                yb[(size_t)o*HW + px] = f2bf(acc[os][ns][r]);
            }
        }
    }
}

// --------------------------------------------------------------- final ----
__global__ __launch_bounds__(256) void finalk(const u16* __restrict__ y3,
                                              const float* __restrict__ x,
                                              const float2* __restrict__ part3,
                                              const float* __restrict__ gamma,
                                              const float* __restrict__ beta,
                                              float* __restrict__ out){
    __shared__ float scl[64], shl[64];
    int tid = threadIdx.x;
    bn_combine(part3, gamma, beta, scl, shl, tid);
    __syncthreads();
#pragma unroll
    for (int it = 0; it < 4; it++){
        int i4 = blockIdx.x*1024 + it*256 + tid;
        int c  = (i4 >> 12) & 63;
        uint2  yv = reinterpret_cast<const uint2*>(y3)[i4];
        float4 bx = reinterpret_cast<const float4*>(x)[i4];
        float s = scl[c], t = shl[c];
        float4 r;
        r.x = fmaf(s, __uint_as_float(yv.x << 16),          t) + bx.x;
        r.y = fmaf(s, __uint_as_float(yv.x & 0xffff0000u),  t) + bx.y;
        r.z = fmaf(s, __uint_as_float(yv.y << 16),          t) + bx.z;
        r.w = fmaf(s, __uint_as_float(yv.y & 0xffff0000u),  t) + bx.w;
        reinterpret_cast<float4*>(out)[i4] = r;
    }
}

// -------------------------------------------------------------- launch ----
extern "C" void kernel_launch(void* const* d_in, const int* in_sizes, int n_in,
                              void* d_out, int out_size, void* d_ws, size_t ws_size,
                              hipStream_t stream){
    const float* x        = (const float*)d_in[0];
    const float* pre_bias = (const float*)d_in[1];
    const float* pre_w    = (const float*)d_in[2];
    const float* pre_g    = (const float*)d_in[3];
    const float* pre_b    = (const float*)d_in[4];
    const float* pre_a    = (const float*)d_in[5];
    const float* mid_bias = (const float*)d_in[6];
    const float* red_w    = (const float*)d_in[7];
    const float* span_w   = (const float*)d_in[8];
    const float* mid_g    = (const float*)d_in[9];
    const float* mid_b    = (const float*)d_in[10];
    const float* post_bias= (const float*)d_in[12];
    const float* post_w   = (const float*)d_in[13];
    const float* post_g   = (const float*)d_in[14];
    const float* post_b   = (const float*)d_in[15];

    float* ws   = (float*)d_ws;
    u16*   y1b  = (u16*)ws;                          // 8.4M bf16 (later y3b)
    u16*   kerb = (u16*)(ws + 4194304);              // 1.18M bf16
    float* Wq   = ws + 4194304 + 589824;             // 4096
    float* M    = Wq + 4096;                         // 576 (pad 640)
    u32*   wb   = (u32*)(M + 640);                   // 128
    float* AB   = (float*)(wb + 128);                // 128
    float2* part1 = (float2*)(AB + 128);             // 512
    float2* part2 = part1 + 512;
    float2* part3 = part2 + 512;

    u16*   y2b = (u16*)d_out;
    float* out = (float*)d_out;

    hipLaunchKernelGGL(prep, dim3(1), dim3(64), 0, stream,
                       pre_w, pre_bias, red_w, span_w, post_w, wb, AB, Wq, M);
    hipLaunchKernelGGL(conv_pre, dim3(NPIX/256), dim3(256), 0, stream,
                       x, wb, AB, y1b);
    hipLaunchKernelGGL(bnp, dim3(512), dim3(256), 0, stream, y1b, part1);
    hipLaunchKernelGGL(kerk, dim3(NPIX/256), dim3(256), 0, stream,
                       y1b, part1, pre_g, pre_b, pre_a, mid_bias, M, kerb);
    hipLaunchKernelGGL(gatherk, dim3(2048), dim3(256), 0, stream,
                       y1b, part1, pre_g, pre_b, pre_a, mid_bias, kerb, y2b);
    hipLaunchKernelGGL(bnp, dim3(512), dim3(256), 0, stream, y2b, part2);
    hipLaunchKernelGGL(conv_post, dim3(512), dim3(256), 0, stream,
                       y2b, part2, mid_g, mid_b, post_bias, Wq, y1b);
    hipLaunchKernelGGL(bnp, dim3(512), dim3(256), 0, stream, y1b, part3);
    hipLaunchKernelGGL(finalk, dim3(2048), dim3(256), 0, stream,
                       y1b, x, part3, post_g, post_b, out);
}